// Round 1
// baseline (153.934 us; speedup 1.0000x reference)
//
#include <hip/hip_runtime.h>
#include <math.h>

#define N_RELS 10
#define N_HID 64

// 16 lanes cooperate per edge: lane sub holds float4 chunk `sub` of the 64-dim row.
__global__ __launch_bounds__(256) void distmult_kernel(
    const float* __restrict__ h,
    const float* __restrict__ W,
    const int* __restrict__ src_idx,
    const int* __restrict__ dst_idx,
    const int* __restrict__ rel_idx,
    float* __restrict__ out,
    int n_edges)
{
    // Stage W (10 x 64 f32 = 2.5 KB) in LDS as float4 rows.
    __shared__ float4 Wl[N_RELS * (N_HID / 4)];
    for (int i = threadIdx.x; i < N_RELS * (N_HID / 4); i += blockDim.x) {
        Wl[i] = reinterpret_cast<const float4*>(W)[i];
    }
    __syncthreads();

    const int sub = threadIdx.x & 15;            // float4 slot within the 64-dim row
    const int group = threadIdx.x >> 4;          // edge-group within block (16 per 256-thr block)
    const int groups_per_block = blockDim.x >> 4;
    const int stride = gridDim.x * groups_per_block;
    const float4* __restrict__ h4 = reinterpret_cast<const float4*>(h);

    for (int e = blockIdx.x * groups_per_block + group; e < n_edges; e += stride) {
        const int s = src_idx[e];
        const int d = dst_idx[e];
        const int r = rel_idx[e];

        const float4 u = h4[(long)s * (N_HID / 4) + sub];
        const float4 v = h4[(long)d * (N_HID / 4) + sub];
        const float4 w = Wl[r * (N_HID / 4) + sub];

        float p = u.x * w.x * v.x
                + u.y * w.y * v.y
                + u.z * w.z * v.z
                + u.w * w.w * v.w;

        // Reduce across the 16-lane group (xor masks stay within the group).
        p += __shfl_xor(p, 1, 64);
        p += __shfl_xor(p, 2, 64);
        p += __shfl_xor(p, 4, 64);
        p += __shfl_xor(p, 8, 64);

        if (sub == 0) {
            out[e] = 1.0f / (1.0f + __expf(-p));
        }
    }
}

extern "C" void kernel_launch(void* const* d_in, const int* in_sizes, int n_in,
                              void* d_out, int out_size, void* d_ws, size_t ws_size,
                              hipStream_t stream) {
    const float* h   = (const float*)d_in[0];
    const float* W   = (const float*)d_in[1];
    const int*   src = (const int*)d_in[2];
    const int*   dst = (const int*)d_in[3];
    const int*   rel = (const int*)d_in[4];
    float* out = (float*)d_out;

    const int n_edges = in_sizes[2];

    const int block = 256;
    const int groups_per_block = block / 16;
    int blocks_needed = (n_edges + groups_per_block - 1) / groups_per_block;
    int grid = blocks_needed < 2048 ? blocks_needed : 2048;

    distmult_kernel<<<grid, block, 0, stream>>>(h, W, src, dst, rel, out, n_edges);
}

// Round 2
// 148.645 us; speedup vs baseline: 1.0356x; 1.0356x over previous
//
#include <hip/hip_runtime.h>
#include <math.h>

#define N_RELS 10
#define N_HID 64
#define EPG 4   // edges per 16-lane group per iteration

__global__ __launch_bounds__(256) void distmult_kernel(
    const float* __restrict__ h,
    const float* __restrict__ W,
    const int* __restrict__ src_idx,
    const int* __restrict__ dst_idx,
    const int* __restrict__ rel_idx,
    float* __restrict__ out,
    int n_edges)
{
    // Stage W (10 x 64 f32 = 2.5 KB) in LDS as float4 rows.
    __shared__ float4 Wl[N_RELS * (N_HID / 4)];
    for (int i = threadIdx.x; i < N_RELS * (N_HID / 4); i += blockDim.x) {
        Wl[i] = reinterpret_cast<const float4*>(W)[i];
    }
    __syncthreads();

    const int sub = threadIdx.x & 15;            // float4 slot within the 64-dim row
    const int group = threadIdx.x >> 4;          // 16 groups per 256-thr block
    const int groups_per_block = blockDim.x >> 4;
    const long stride = (long)gridDim.x * groups_per_block * EPG;
    const float4* __restrict__ h4 = reinterpret_cast<const float4*>(h);

    for (long base = ((long)blockIdx.x * groups_per_block + group) * EPG;
         base < n_edges; base += stride) {

        float p0, p1, p2, p3;

        if (base + EPG <= n_edges) {
            // Vector index loads: 16B each, broadcast across the group.
            const int4 s4 = *reinterpret_cast<const int4*>(&src_idx[base]);
            const int4 d4 = *reinterpret_cast<const int4*>(&dst_idx[base]);
            const int4 r4 = *reinterpret_cast<const int4*>(&rel_idx[base]);

            // 8 independent row gathers in flight.
            const float4 u0 = h4[(long)s4.x * (N_HID / 4) + sub];
            const float4 u1 = h4[(long)s4.y * (N_HID / 4) + sub];
            const float4 u2 = h4[(long)s4.z * (N_HID / 4) + sub];
            const float4 u3 = h4[(long)s4.w * (N_HID / 4) + sub];
            const float4 v0 = h4[(long)d4.x * (N_HID / 4) + sub];
            const float4 v1 = h4[(long)d4.y * (N_HID / 4) + sub];
            const float4 v2 = h4[(long)d4.z * (N_HID / 4) + sub];
            const float4 v3 = h4[(long)d4.w * (N_HID / 4) + sub];

            const float4 w0 = Wl[r4.x * (N_HID / 4) + sub];
            const float4 w1 = Wl[r4.y * (N_HID / 4) + sub];
            const float4 w2 = Wl[r4.z * (N_HID / 4) + sub];
            const float4 w3 = Wl[r4.w * (N_HID / 4) + sub];

            p0 = u0.x*w0.x*v0.x + u0.y*w0.y*v0.y + u0.z*w0.z*v0.z + u0.w*w0.w*v0.w;
            p1 = u1.x*w1.x*v1.x + u1.y*w1.y*v1.y + u1.z*w1.z*v1.z + u1.w*w1.w*v1.w;
            p2 = u2.x*w2.x*v2.x + u2.y*w2.y*v2.y + u2.z*w2.z*v2.z + u2.w*w2.w*v2.w;
            p3 = u3.x*w3.x*v3.x + u3.y*w3.y*v3.y + u3.z*w3.z*v3.z + u3.w*w3.w*v3.w;
        } else {
            // Tail: per-edge guarded path.
            float pt[EPG];
            #pragma unroll
            for (int k = 0; k < EPG; ++k) {
                long e = base + k;
                if (e < n_edges) {
                    int s = src_idx[e], d = dst_idx[e], r = rel_idx[e];
                    float4 u = h4[(long)s * (N_HID / 4) + sub];
                    float4 v = h4[(long)d * (N_HID / 4) + sub];
                    float4 w = Wl[r * (N_HID / 4) + sub];
                    pt[k] = u.x*w.x*v.x + u.y*w.y*v.y + u.z*w.z*v.z + u.w*w.w*v.w;
                } else {
                    pt[k] = 0.0f;
                }
            }
            p0 = pt[0]; p1 = pt[1]; p2 = pt[2]; p3 = pt[3];
        }

        // Butterfly reduce across the 16-lane group for all 4 edges.
        #pragma unroll
        for (int m = 1; m < 16; m <<= 1) {
            p0 += __shfl_xor(p0, m, 64);
            p1 += __shfl_xor(p1, m, 64);
            p2 += __shfl_xor(p2, m, 64);
            p3 += __shfl_xor(p3, m, 64);
        }

        // Lanes 0..3 write 4 adjacent edges: one contiguous 16B store per group.
        if (sub < EPG) {
            long e = base + sub;
            if (e < n_edges) {
                float p = (sub == 0) ? p0 : (sub == 1) ? p1 : (sub == 2) ? p2 : p3;
                out[e] = 1.0f / (1.0f + __expf(-p));
            }
        }
    }
}

extern "C" void kernel_launch(void* const* d_in, const int* in_sizes, int n_in,
                              void* d_out, int out_size, void* d_ws, size_t ws_size,
                              hipStream_t stream) {
    const float* h   = (const float*)d_in[0];
    const float* W   = (const float*)d_in[1];
    const int*   src = (const int*)d_in[2];
    const int*   dst = (const int*)d_in[3];
    const int*   rel = (const int*)d_in[4];
    float* out = (float*)d_out;

    const int n_edges = in_sizes[2];

    const int block = 256;
    const int groups_per_block = block / 16;           // 16 groups
    const int edges_per_block = groups_per_block * EPG; // 64
    int blocks_needed = (n_edges + edges_per_block - 1) / edges_per_block;
    int grid = blocks_needed < 2048 ? blocks_needed : 2048;

    distmult_kernel<<<grid, block, 0, stream>>>(h, W, src, dst, rel, out, n_edges);
}

// Round 3
// 105.523 us; speedup vs baseline: 1.4588x; 1.4087x over previous
//
#include <hip/hip_runtime.h>
#include <hip/hip_fp16.h>
#include <math.h>

#define N_RELS 10
#define N_HID 64

// ---------------- Kernel 1: h fp32 -> fp16 (RNE) into workspace ----------------
__global__ __launch_bounds__(256) void cvt_fp16_kernel(
    const float* __restrict__ h,
    unsigned short* __restrict__ hh,
    long n)  // n = total floats, multiple of 8
{
    long i = (long)blockIdx.x * blockDim.x + threadIdx.x;
    long stride = (long)gridDim.x * blockDim.x;
    const float4* __restrict__ h4 = reinterpret_cast<const float4*>(h);
    uint4* __restrict__ o4 = reinterpret_cast<uint4*>(hh);
    long n8 = n >> 3;
    for (long k = i; k < n8; k += stride) {
        float4 a = h4[2 * k];
        float4 b = h4[2 * k + 1];
        __half2 p0 = __floats2half2_rn(a.x, a.y);
        __half2 p1 = __floats2half2_rn(a.z, a.w);
        __half2 p2 = __floats2half2_rn(b.x, b.y);
        __half2 p3 = __floats2half2_rn(b.z, b.w);
        uint4 o;
        o.x = *reinterpret_cast<unsigned int*>(&p0);
        o.y = *reinterpret_cast<unsigned int*>(&p1);
        o.z = *reinterpret_cast<unsigned int*>(&p2);
        o.w = *reinterpret_cast<unsigned int*>(&p3);
        o4[k] = o;
    }
}

// ---------------- Kernel 2: gather fp16 rows, dot, sigmoid ----------------
// 8 lanes per edge: lane sub holds dims [sub*8, sub*8+8) as one uint4 (8 halves).
#define EPG 4
__global__ __launch_bounds__(256) void distmult_fp16_kernel(
    const unsigned short* __restrict__ hh,   // [N, 64] fp16
    const float* __restrict__ W,
    const int* __restrict__ src_idx,
    const int* __restrict__ dst_idx,
    const int* __restrict__ rel_idx,
    float* __restrict__ out,
    int n_edges)
{
    __shared__ float Wl[N_RELS * N_HID];
    for (int i = threadIdx.x; i < N_RELS * (N_HID / 4); i += blockDim.x) {
        reinterpret_cast<float4*>(Wl)[i] = reinterpret_cast<const float4*>(W)[i];
    }
    __syncthreads();

    const int sub = threadIdx.x & 7;          // lane within 8-lane edge group
    const int group = threadIdx.x >> 3;       // 32 groups per 256-thr block
    const int groups_per_block = blockDim.x >> 3;
    const long stride = (long)gridDim.x * groups_per_block * EPG;
    const uint4* __restrict__ h8 = reinterpret_cast<const uint4*>(hh); // 8 uint4 per row

    for (long base = ((long)blockIdx.x * groups_per_block + group) * EPG;
         base < n_edges; base += stride) {

        float p[EPG];

        if (base + EPG <= n_edges) {
            const int4 s4 = *reinterpret_cast<const int4*>(&src_idx[base]);
            const int4 d4 = *reinterpret_cast<const int4*>(&dst_idx[base]);
            const int4 r4 = *reinterpret_cast<const int4*>(&rel_idx[base]);

            // 8 independent 16B gathers in flight (4 src rows + 4 dst rows).
            const uint4 u0 = h8[(long)s4.x * 8 + sub];
            const uint4 u1 = h8[(long)s4.y * 8 + sub];
            const uint4 u2 = h8[(long)s4.z * 8 + sub];
            const uint4 u3 = h8[(long)s4.w * 8 + sub];
            const uint4 v0 = h8[(long)d4.x * 8 + sub];
            const uint4 v1 = h8[(long)d4.y * 8 + sub];
            const uint4 v2 = h8[(long)d4.z * 8 + sub];
            const uint4 v3 = h8[(long)d4.w * 8 + sub];

            const int rr[EPG] = {r4.x, r4.y, r4.z, r4.w};
            const uint4 uu[EPG] = {u0, u1, u2, u3};
            const uint4 vv[EPG] = {v0, v1, v2, v3};

            #pragma unroll
            for (int k = 0; k < EPG; ++k) {
                const float* wp = &Wl[rr[k] * N_HID + sub * 8];
                const __half2* up = reinterpret_cast<const __half2*>(&uu[k]);
                const __half2* vp = reinterpret_cast<const __half2*>(&vv[k]);
                float acc = 0.0f;
                #pragma unroll
                for (int j = 0; j < 4; ++j) {
                    float2 uf = __half22float2(up[j]);
                    float2 vf = __half22float2(vp[j]);
                    acc += uf.x * wp[2 * j] * vf.x;
                    acc += uf.y * wp[2 * j + 1] * vf.y;
                }
                p[k] = acc;
            }
        } else {
            #pragma unroll
            for (int k = 0; k < EPG; ++k) {
                long e = base + k;
                if (e < n_edges) {
                    int s = src_idx[e], d = dst_idx[e], r = rel_idx[e];
                    uint4 u = h8[(long)s * 8 + sub];
                    uint4 v = h8[(long)d * 8 + sub];
                    const float* wp = &Wl[r * N_HID + sub * 8];
                    const __half2* up = reinterpret_cast<const __half2*>(&u);
                    const __half2* vp = reinterpret_cast<const __half2*>(&v);
                    float acc = 0.0f;
                    #pragma unroll
                    for (int j = 0; j < 4; ++j) {
                        float2 uf = __half22float2(up[j]);
                        float2 vf = __half22float2(vp[j]);
                        acc += uf.x * wp[2 * j] * vf.x;
                        acc += uf.y * wp[2 * j + 1] * vf.y;
                    }
                    p[k] = acc;
                } else {
                    p[k] = 0.0f;
                }
            }
        }

        // Reduce across the 8-lane group (masks stay within the group).
        #pragma unroll
        for (int k = 0; k < EPG; ++k) {
            p[k] += __shfl_xor(p[k], 1, 64);
            p[k] += __shfl_xor(p[k], 2, 64);
            p[k] += __shfl_xor(p[k], 4, 64);
        }

        // Lanes 0..3 write 4 adjacent edges: one contiguous 16B store per group.
        if (sub < EPG) {
            long e = base + sub;
            if (e < n_edges) {
                float pv = p[sub];
                out[e] = 1.0f / (1.0f + __expf(-pv));
            }
        }
    }
}

// ---------------- Fallback fp32 kernel (if workspace too small) ----------------
__global__ __launch_bounds__(256) void distmult_fp32_kernel(
    const float* __restrict__ h,
    const float* __restrict__ W,
    const int* __restrict__ src_idx,
    const int* __restrict__ dst_idx,
    const int* __restrict__ rel_idx,
    float* __restrict__ out,
    int n_edges)
{
    __shared__ float4 Wl[N_RELS * (N_HID / 4)];
    for (int i = threadIdx.x; i < N_RELS * (N_HID / 4); i += blockDim.x) {
        Wl[i] = reinterpret_cast<const float4*>(W)[i];
    }
    __syncthreads();

    const int sub = threadIdx.x & 15;
    const int group = threadIdx.x >> 4;
    const int groups_per_block = blockDim.x >> 4;
    const long stride = (long)gridDim.x * groups_per_block;
    const float4* __restrict__ h4 = reinterpret_cast<const float4*>(h);

    for (long e = (long)blockIdx.x * groups_per_block + group; e < n_edges; e += stride) {
        int s = src_idx[e], d = dst_idx[e], r = rel_idx[e];
        float4 u = h4[(long)s * 16 + sub];
        float4 v = h4[(long)d * 16 + sub];
        float4 w = Wl[r * 16 + sub];
        float p = u.x*w.x*v.x + u.y*w.y*v.y + u.z*w.z*v.z + u.w*w.w*v.w;
        p += __shfl_xor(p, 1, 64);
        p += __shfl_xor(p, 2, 64);
        p += __shfl_xor(p, 4, 64);
        p += __shfl_xor(p, 8, 64);
        if (sub == 0) out[e] = 1.0f / (1.0f + __expf(-p));
    }
}

extern "C" void kernel_launch(void* const* d_in, const int* in_sizes, int n_in,
                              void* d_out, int out_size, void* d_ws, size_t ws_size,
                              hipStream_t stream) {
    const float* h   = (const float*)d_in[0];
    const float* W   = (const float*)d_in[1];
    const int*   src = (const int*)d_in[2];
    const int*   dst = (const int*)d_in[3];
    const int*   rel = (const int*)d_in[4];
    float* out = (float*)d_out;

    const long n_h = in_sizes[0];          // 500000 * 64 floats
    const int n_edges = in_sizes[2];
    const size_t need = (size_t)n_h * sizeof(unsigned short);

    if (ws_size >= need) {
        unsigned short* hh = (unsigned short*)d_ws;

        // Pass 1: fp32 -> fp16 conversion (streaming, ~40us).
        cvt_fp16_kernel<<<2048, 256, 0, stream>>>(h, hh, n_h);

        // Pass 2: gather + dot + sigmoid. 128 edges/block, exact grid (no tail
        // imbalance: 2M / 128 = 15625).
        const int block = 256;
        const int edges_per_block = (block / 8) * EPG;  // 128
        int grid = (n_edges + edges_per_block - 1) / edges_per_block;
        distmult_fp16_kernel<<<grid, block, 0, stream>>>(hh, W, src, dst, rel, out, n_edges);
    } else {
        const int block = 256;
        const int groups_per_block = block / 16;
        int blocks_needed = (n_edges + groups_per_block - 1) / groups_per_block;
        int grid = blocks_needed < 2048 ? blocks_needed : 2048;
        distmult_fp32_kernel<<<grid, block, 0, stream>>>(h, W, src, dst, rel, out, n_edges);
    }
}